// Round 1
// 412.705 us; speedup vs baseline: 1.0087x; 1.0087x over previous
//
#include <hip/hip_runtime.h>

// Problem constants
#define NPG   39
#define NGRAPH 8192
#define EPG   312           // input edges per graph
#define EDG   351           // + 39 self loops
#define E0    2555904       // total input edges (8192*312)
#define FDIM  4560
#define KP    4608          // padded K for bf16 GEMM (multiple of 128)

typedef __bf16 bf16x8 __attribute__((ext_vector_type(8)));
typedef float  f32x4  __attribute__((ext_vector_type(4)));
typedef float  f32x2  __attribute__((ext_vector_type(2)));

__device__ __forceinline__ unsigned short f2b(float f) {
  unsigned int u = __float_as_uint(f);
  u += 0x7fffu + ((u >> 16) & 1u);            // RNE to bf16
  return (unsigned short)(u >> 16);
}
__device__ __forceinline__ f32x4 vmax4(f32x4 a, f32x4 b) {
  f32x4 r; r.x = fmaxf(a.x, b.x); r.y = fmaxf(a.y, b.y);
  r.z = fmaxf(a.z, b.z); r.w = fmaxf(a.w, b.w); return r;
}
// wave-level "barrier": single wave per workgroup -> only need LDS drain +
// a compiler ordering fence (lockstep execution gives cross-lane sync).
__device__ __forceinline__ void wsync() {
  asm volatile("s_waitcnt lgkmcnt(0)" ::: "memory");
}

// =================== per-graph LDS (one wave per graph) ===================
// A: layer inputs / aggregated outputs. strides: x=1, l1out=12, l2out=64(swz),
//    l3out=36, l4out=12.  B: matmul outputs h1. strides: 12, 64(swz), 32(swz), 12.
__shared__ alignas(16) float Abuf[NPG * 64];       // 9984 B
__shared__ alignas(16) float Bbuf[NPG * 64];       // 9984 B
__shared__ alignas(16) float alf[352];             // edge weights (aliased as cnt during build)
__shared__ alignas(16) float bl[64];               // padded bias
__shared__ float sn[40];
__shared__ float dn[40];                           // d_n, then 1/den
__shared__ unsigned short csr_src[352];
__shared__ unsigned short csr_ptr[40];

// ======================= fused GAT layer (per wave) =======================
template<int Fi, int Fo, int SAin, int SAout, int SB,
         bool SWZAin, bool SWZAout, bool SWZB>
__device__ __forceinline__ void layer(const float* __restrict__ W,   // [Fi][Fo] row-major (original layout)
                                      const float* __restrict__ as_,
                                      const float* __restrict__ ad_,
                                      const float* __restrict__ bias,
                                      unsigned short* __restrict__ f_row,
                                      int res_off, int out_off, int lane) {
  constexpr int  OQ = (Fo + 3) / 4;                // output quads
  constexpr bool PP = (OQ & (OQ - 1)) == 0;        // pow2 -> register pooling

  bl[lane] = (lane < Fo) ? bias[lane] : 0.f;       // padded bias stage

  // ---------- P1: h1 = h0 @ W (lane = node, W via scalar loads) ----------
  // ---------- P2: attention scalars + h1 -> B ----------
  if (lane < NPG) {
    float h0r[(Fi < 4) ? 4 : Fi];
    if constexpr (Fi == 1) {
      h0r[0] = Abuf[lane];
    } else {
#pragma unroll
      for (int iq = 0; iq < Fi / 4; ++iq) {
        int qq = SWZAin ? (iq ^ (lane & 7)) : iq;
        f32x4 v = *(const f32x4*)&Abuf[lane * SAin + 4 * qq];
        h0r[4 * iq] = v.x; h0r[4 * iq + 1] = v.y;
        h0r[4 * iq + 2] = v.z; h0r[4 * iq + 3] = v.w;
      }
    }
    float h1r[OQ * 4];
#pragma unroll
    for (int o = 0; o < OQ * 4; ++o) h1r[o] = 0.f;
#pragma unroll
    for (int i = 0; i < Fi; ++i) {
      float xv = h0r[i];
      if constexpr ((Fo & 1) == 0) {               // packed f32 pairs -> v_pk_fma
#pragma unroll
        for (int op = 0; op < Fo / 2; ++op) {
          f32x2 wv = *(const f32x2*)&W[i * Fo + 2 * op];
          f32x2 hv = *(f32x2*)&h1r[2 * op];
          hv += wv * xv;
          *(f32x2*)&h1r[2 * op] = hv;
        }
      } else {
#pragma unroll
        for (int o = 0; o < Fo; ++o) h1r[o] += xv * W[i * Fo + o];
      }
    }
    float s_ = 0.f, d_ = 0.f;
#pragma unroll
    for (int o = 0; o < Fo; ++o) { s_ += h1r[o] * as_[o]; d_ += h1r[o] * ad_[o]; }
    sn[lane] = s_; dn[lane] = d_;
#pragma unroll
    for (int q = 0; q < OQ; ++q) {                 // h1 -> B (bank-swizzled)
      int qq = SWZB ? (q ^ (lane & 7)) : q;
      f32x4 v; v.x = h1r[4 * q]; v.y = h1r[4 * q + 1];
      v.z = h1r[4 * q + 2]; v.w = h1r[4 * q + 3];
      *(f32x4*)&Bbuf[lane * SB + 4 * qq] = v;
    }
  }
  wsync();

  // ---------- P3: per-dst softmax (1/den folded into P4) ----------
  if (lane < NPG) {
    int rs = csr_ptr[lane], re = csr_ptr[lane + 1];
    float dv = dn[lane];
    float m = -3.4e38f;
    for (int k = rs; k < re; ++k) {
      float e = sn[csr_src[k]] + dv;
      e = (e >= 0.f) ? e : 0.2f * e;               // leaky_relu 0.2
      alf[k] = e;
      m = fmaxf(m, e);
    }
    float den = 0.f;
    for (int k = rs; k < re; ++k) { float w = __expf(alf[k] - m); alf[k] = w; den += w; }
    dn[lane] = 1.f / (den + 1e-16f);
  }
  wsync();

  // ---------- P4: aggregate + bias + relu + res write + (pool acc) ----------
  f32x4 pm = {0.f, 0.f, 0.f, 0.f};                 // post-relu values >= 0
  for (int item = lane; item < NPG * OQ; item += 64) {
    int d = item / OQ, q = item - d * OQ;
    int rs = csr_ptr[d], re = csr_ptr[d + 1];
    f32x4 acc = {0.f, 0.f, 0.f, 0.f};
    for (int k = rs; k < re; ++k) {
      float w = alf[k];
      int s = csr_src[k];
      int qq = SWZB ? (q ^ (s & 7)) : q;
      f32x4 hv = *(const f32x4*)&Bbuf[s * SB + 4 * qq];
      acc += hv * w;
    }
    float inv = dn[d];
    f32x4 bv = *(const f32x4*)&bl[4 * q];
    acc = acc * inv + bv;
    f32x4 z = {0.f, 0.f, 0.f, 0.f};
    acc = vmax4(acc, z);
    int qo = SWZAout ? (q ^ (d & 7)) : q;
    *(f32x4*)&Abuf[d * SAout + 4 * qo] = acc;      // next layer input
#pragma unroll
    for (int j = 0; j < 4; ++j)
      if (4 * q + j < Fo) f_row[res_off + d * Fo + 4 * q + j] = f2b(acc[j]);
    if constexpr (PP) pm = vmax4(pm, acc);
  }
  wsync();

  // ---------- P5: per-graph max pool ----------
  if constexpr (PP) {
    // lane's q-class is fixed across its P4 items (64 % OQ == 0): reduce
    // across d-groups with shfl_xor, lanes 0..OQ-1 hold the result.
#pragma unroll
    for (int st = OQ; st < 64; st <<= 1) {
      f32x4 o;
      o.x = __shfl_xor(pm.x, st); o.y = __shfl_xor(pm.y, st);
      o.z = __shfl_xor(pm.z, st); o.w = __shfl_xor(pm.w, st);
      pm = vmax4(pm, o);
    }
    if (lane < OQ) {
#pragma unroll
      for (int j = 0; j < 4; ++j)
        if (4 * lane + j < Fo) f_row[out_off + 4 * lane + j] = f2b(pm[j]);
    }
  } else {
    int g = lane >> 4, q = lane & 15;
    if (q < OQ) {
      f32x4 m = {0.f, 0.f, 0.f, 0.f};
      for (int r = g; r < NPG; r += 4) {
        int qq = SWZAout ? (q ^ (r & 7)) : q;
        m = vmax4(m, *(const f32x4*)&Abuf[r * SAout + 4 * qq]);
      }
#pragma unroll
      for (int j = 0; j < 4; ++j) {
        float t;
        t = __shfl_xor(m[j], 16); m[j] = fmaxf(m[j], t);
        t = __shfl_xor(m[j], 32); m[j] = fmaxf(m[j], t);
      }
      if (g == 0) {
#pragma unroll
        for (int j = 0; j < 4; ++j)
          if (4 * q + j < Fo) f_row[out_off + 4 * q + j] = f2b(m[j]);
      }
    }
  }
}

// =========================== fused GAT kernel ===========================
__global__ __launch_bounds__(64, 2) void gat_fused(
    const float* __restrict__ x, const int* __restrict__ ei,
    const float* __restrict__ W1, const float* __restrict__ as1, const float* __restrict__ ad1, const float* __restrict__ b1,
    const float* __restrict__ W2, const float* __restrict__ as2, const float* __restrict__ ad2, const float* __restrict__ b2,
    const float* __restrict__ W3, const float* __restrict__ as3, const float* __restrict__ ad3, const float* __restrict__ b3,
    const float* __restrict__ W4, const float* __restrict__ as4, const float* __restrict__ ad4, const float* __restrict__ b4,
    unsigned short* __restrict__ f) {
  const int b = blockIdx.x;
  const int lane = threadIdx.x;                    // one wave per graph
  const int base = b * NPG;
  const int* srcg = ei + (size_t)b * EPG;
  const int* dstg = ei + E0 + (size_t)b * EPG;
  unsigned short* f_row = f + (size_t)b * KP;
  int* cnt = (int*)alf;                            // alias: alf unused until P3

  // x load, res0, out0, K-pad zero
  float xv = 0.f;
  if (lane < NPG) {
    xv = x[(size_t)base + lane];
    Abuf[lane] = xv;
    f_row[lane] = f2b(xv);
  }
  if (lane < KP - FDIM) f_row[FDIM + lane] = 0;    // bf16 zero pad
  float mx = (lane < NPG) ? xv : -3.4e38f;
#pragma unroll
  for (int st = 1; st < 64; st <<= 1) { float t = __shfl_xor(mx, st); mx = fmaxf(mx, t); }
  if (lane == 0) f_row[4446] = f2b(mx);            // out0 = max over raw x
  if (lane < NPG) cnt[lane] = 1;                   // self loop pre-count
  wsync();

  // degree count (edges stashed in registers for the scatter pass)
  int es[5], ed[5];
#pragma unroll
  for (int it = 0; it < 5; ++it) {
    int e = lane + 64 * it;
    if (e < EPG) {
      int s = srcg[e] - base, d = dstg[e] - base;
      s = min(max(s, 0), NPG - 1);
      d = min(max(d, 0), NPG - 1);
      es[it] = s; ed[it] = d;
      atomicAdd(&cnt[d], 1);
    } else { es[it] = -1; ed[it] = 0; }
  }
  wsync();

  // exclusive prefix sum via wave scan
  int c = (lane < NPG) ? cnt[lane] : 0;
  int v = c;
#pragma unroll
  for (int off = 1; off < 64; off <<= 1) { int t = __shfl_up(v, off); if (lane >= off) v += t; }
  int excl = v - c;
  if (lane < NPG) csr_ptr[lane] = (unsigned short)excl;
  if (lane == NPG - 1) csr_ptr[NPG] = (unsigned short)EDG;   // total is always 351
  wsync();
  if (lane < NPG) cnt[lane] = excl;                // running positions
  wsync();

  // scatter: self loops + edges
  if (lane < NPG) { int p = atomicAdd(&cnt[lane], 1); csr_src[p] = (unsigned short)lane; }
#pragma unroll
  for (int it = 0; it < 5; ++it) {
    if (es[it] >= 0) {
      int p = atomicAdd(&cnt[ed[it]], 1);
      p = min(p, EDG - 1);
      csr_src[p] = (unsigned short)es[it];
    }
  }
  wsync();

  //     Fi  Fo  SAin SAout SB  swzAin swzAout swzB
  layer< 1,  8,  1,   12,  12, false, false, false>(W1, as1, ad1, b1, f_row, 39,   4447, lane);
  layer< 8, 64, 12,   64,  64, false, true,  true >(W2, as2, ad2, b2, f_row, 351,  4455, lane);
  layer<64, 32, 64,   36,  32, true,  false, true >(W3, as3, ad3, b3, f_row, 2847, 4519, lane);
  layer<32,  9, 36,   12,  12, false, false, false>(W4, as4, ad4, b4, f_row, 4095, 4551, lane);
}

// ================= weight transpose + bf16 cast (per launch) =================
__global__ __launch_bounds__(256) void tcast(const float* __restrict__ in,
                                             unsigned short* __restrict__ out,
                                             int K, int NN, int Kpad) {
  __shared__ float tile[64 * 65];
  const int k0 = blockIdx.x * 64, n0 = blockIdx.y * 64;
  const int tid = threadIdx.x;
#pragma unroll
  for (int i = 0; i < 16; ++i) {
    int idx = i * 256 + tid;
    int r = idx >> 6, c = idx & 63;
    int k = k0 + r;
    tile[r * 65 + c] = (k < K) ? in[(size_t)k * NN + n0 + c] : 0.f;
  }
  __syncthreads();
#pragma unroll
  for (int i = 0; i < 16; ++i) {
    int idx = i * 256 + tid;
    int r = idx >> 6, c = idx & 63;    // r: n-offset, c: k-offset
    out[(size_t)(n0 + r) * Kpad + k0 + c] = f2b(tile[c * 65 + r]);
  }
}

// =========================== bf16 MFMA GEMM ===========================
template<bool OUT_BF16>
__global__ __launch_bounds__(256) void mfma_gemm(const unsigned short* __restrict__ A,
    const unsigned short* __restrict__ Bt, unsigned short* __restrict__ Cb,
    float* __restrict__ Cf, const float* __restrict__ bias, int K, int N) {
  __shared__ alignas(16) unsigned short As[128 * 32];
  __shared__ alignas(16) unsigned short Bs[128 * 32];
  const int tid = threadIdx.x;
  const int lane = tid & 63;
  const int wave = tid >> 6;
  const int wy = wave >> 1, wx = wave & 1;
  const int m0 = blockIdx.y * 128, n0 = blockIdx.x * 128;

  f32x4 acc[4][4];
  const f32x4 z = {0.f, 0.f, 0.f, 0.f};
#pragma unroll
  for (int i = 0; i < 4; ++i)
#pragma unroll
    for (int j = 0; j < 4; ++j) acc[i][j] = z;

  const int lr = lane >> 2;
  const int lc = (lane & 3) * 8;
  const int q8 = (lane >> 4) * 8;
  const int rm = lane & 15;

  for (int k0 = 0; k0 < K; k0 += 32) {
    __syncthreads();
#pragma unroll
    for (int t = 0; t < 2; ++t) {
      int r0 = wave * 32 + t * 16;
      const unsigned short* ga = A  + (size_t)(m0 + r0 + lr) * K + k0 + lc;
      const unsigned short* gb = Bt + (size_t)(n0 + r0 + lr) * K + k0 + lc;
      __builtin_amdgcn_global_load_lds(
          (const __attribute__((address_space(1))) unsigned int*)(const void*)ga,
          (__attribute__((address_space(3))) unsigned int*)(void*)&As[r0 * 32], 16, 0, 0);
      __builtin_amdgcn_global_load_lds(
          (const __attribute__((address_space(1))) unsigned int*)(const void*)gb,
          (__attribute__((address_space(3))) unsigned int*)(void*)&Bs[r0 * 32], 16, 0, 0);
    }
    __syncthreads();
    bf16x8 af[4], bfr[4];
#pragma unroll
    for (int i = 0; i < 4; ++i) {
      af[i]  = *(const bf16x8*)&As[(wy * 64 + i * 16 + rm) * 32 + q8];
      bfr[i] = *(const bf16x8*)&Bs[(wx * 64 + i * 16 + rm) * 32 + q8];
    }
#pragma unroll
    for (int i = 0; i < 4; ++i)
#pragma unroll
      for (int j = 0; j < 4; ++j)
        acc[i][j] = __builtin_amdgcn_mfma_f32_16x16x32_bf16(af[i], bfr[j], acc[i][j], 0, 0, 0);
  }
  const int q4 = (lane >> 4) * 4;
#pragma unroll
  for (int i = 0; i < 4; ++i) {
#pragma unroll
    for (int j = 0; j < 4; ++j) {
      int row = m0 + wy * 64 + i * 16 + q4;
      int col = n0 + wx * 64 + j * 16 + rm;
      float bv = bias[col];
#pragma unroll
      for (int v = 0; v < 4; ++v) {
        float val = fmaxf(acc[i][j][v] + bv, 0.f);
        if constexpr (OUT_BF16) Cb[(size_t)(row + v) * N + col] = f2b(val);
        else                    Cf[(size_t)(row + v) * N + col] = val;
      }
    }
  }
}

// =========================== final 128->9 layer ===========================
__global__ __launch_bounds__(256) void mlp3(const float* __restrict__ g2,
                                            const float* __restrict__ w3,
                                            const float* __restrict__ b3,
                                            float* __restrict__ out) {
  __shared__ float gs[64 * 130];
  __shared__ float ws3[128 * 9];
  const int r0 = blockIdx.x * 64;
  const int tid = threadIdx.x;
  for (int i = tid; i < 64 * 128; i += 256)
    gs[(i >> 7) * 130 + (i & 127)] = g2[(size_t)r0 * 128 + i];
  for (int i = tid; i < 128 * 9; i += 256) ws3[i] = w3[i];
  __syncthreads();
  for (int idx = tid; idx < 64 * 9; idx += 256) {
    int r = idx / 9, c = idx - r * 9;
    float acc = b3[c];
#pragma unroll 8
    for (int k = 0; k < 128; ++k) acc += gs[r * 130 + k] * ws3[k * 9 + c];
    out[(size_t)(r0 + r) * 9 + c] = acc;
  }
}

// =========================== launch ===========================
extern "C" void kernel_launch(void* const* d_in, const int* in_sizes, int n_in,
                              void* d_out, int out_size, void* d_ws, size_t ws_size,
                              hipStream_t stream) {
  const float* x   = (const float*)d_in[0];
  const int*   ei  = (const int*)d_in[1];
  const float* W1  = (const float*)d_in[3];
  const float* as1 = (const float*)d_in[4];
  const float* ad1 = (const float*)d_in[5];
  const float* b1  = (const float*)d_in[6];
  const float* W2  = (const float*)d_in[7];
  const float* as2 = (const float*)d_in[8];
  const float* ad2 = (const float*)d_in[9];
  const float* b2  = (const float*)d_in[10];
  const float* W3  = (const float*)d_in[11];
  const float* as3 = (const float*)d_in[12];
  const float* ad3 = (const float*)d_in[13];
  const float* b3  = (const float*)d_in[14];
  const float* W4  = (const float*)d_in[15];
  const float* as4 = (const float*)d_in[16];
  const float* ad4 = (const float*)d_in[17];
  const float* b4  = (const float*)d_in[18];
  const float* lw1 = (const float*)d_in[19];
  const float* lb1 = (const float*)d_in[20];
  const float* lw2 = (const float*)d_in[21];
  const float* lb2 = (const float*)d_in[22];
  const float* lw3 = (const float*)d_in[23];
  const float* lb3 = (const float*)d_in[24];
  float* out = (float*)d_out;

  // workspace carve-up (bf16 stored as u16)
  unsigned short* f   = (unsigned short*)d_ws;            // [8192][4608] bf16
  unsigned short* w1t = f   + (size_t)NGRAPH * KP;        // [1024][4608] bf16
  unsigned short* w2t = w1t + (size_t)1024 * KP;          // [128][1024]  bf16
  unsigned short* g1  = w2t + (size_t)128 * 1024;         // [8192][1024] bf16
  float*          g2  = (float*)(g1 + (size_t)NGRAPH * 1024); // [8192][128] f32

  tcast<<<dim3(KP / 64, 1024 / 64), 256, 0, stream>>>(lw1, w1t, FDIM, 1024, KP);
  tcast<<<dim3(1024 / 64, 128 / 64), 256, 0, stream>>>(lw2, w2t, 1024, 128, 1024);

  gat_fused<<<NGRAPH, 64, 0, stream>>>(x, ei,
      W1, as1, ad1, b1, W2, as2, ad2, b2, W3, as3, ad3, b3, W4, as4, ad4, b4, f);

  mfma_gemm<true ><<<dim3(1024 / 128, NGRAPH / 128), 256, 0, stream>>>(
      f, w1t, g1, nullptr, lb1, KP, 1024);
  mfma_gemm<false><<<dim3(128 / 128, NGRAPH / 128), 256, 0, stream>>>(
      g1, w2t, nullptr, g2, lb2, 1024, 128);

  mlp3<<<NGRAPH / 64, 256, 0, stream>>>(g2, lw3, lb3, out);
}

// Round 2
// 348.979 us; speedup vs baseline: 1.1929x; 1.1826x over previous
//
#include <hip/hip_runtime.h>

// Problem constants
#define NPG   39
#define NGRAPH 8192
#define EPG   312           // input edges per graph
#define EDG   351           // + 39 self loops
#define E0    2555904       // total input edges (8192*312)
#define FDIM  4560
#define KP    4608          // padded K for bf16 GEMM (multiple of 128)

typedef __bf16 bf16x8 __attribute__((ext_vector_type(8)));
typedef float  f32x4  __attribute__((ext_vector_type(4)));
typedef float  f32x2  __attribute__((ext_vector_type(2)));

__device__ __forceinline__ unsigned short f2b(float f) {
  unsigned int u = __float_as_uint(f);
  u += 0x7fffu + ((u >> 16) & 1u);            // RNE to bf16
  return (unsigned short)(u >> 16);
}
__device__ __forceinline__ float b2f_lo(unsigned int u) { return __uint_as_float(u << 16); }
__device__ __forceinline__ float b2f_hi(unsigned int u) { return __uint_as_float(u & 0xffff0000u); }
__device__ __forceinline__ f32x4 vmax4(f32x4 a, f32x4 b) {
  f32x4 r; r.x = fmaxf(a.x, b.x); r.y = fmaxf(a.y, b.y);
  r.z = fmaxf(a.z, b.z); r.w = fmaxf(a.w, b.w); return r;
}
__device__ __forceinline__ ushort4 pack4(f32x4 v) {
  ushort4 p; p.x = f2b(v.x); p.y = f2b(v.y); p.z = f2b(v.z); p.w = f2b(v.w); return p;
}
// wave-level "barrier": single wave per workgroup -> only need LDS drain +
// a compiler ordering fence (lockstep execution gives cross-lane sync).
__device__ __forceinline__ void wsync() {
  asm volatile("s_waitcnt lgkmcnt(0)" ::: "memory");
}

// =================== per-graph LDS (one wave per graph) ===================
// Feature buffers in bf16 (values identical to the bf16 residuals written to f).
// Row strides in elements: 12 / 68 / 36 / 12 — each stride/4 is odd => full
// bank-pair rotation row-to-row, no XOR swizzle needed. Total LDS ~12.7 KB
// => 12 single-wave blocks/CU (3 waves/SIMD) vs 7 before.
__shared__ alignas(16) unsigned short Abuf16[NPG * 68];  // 5304 B  layer inputs/outputs
__shared__ alignas(16) unsigned short Bbuf16[NPG * 68];  // 5304 B  matmul h1
__shared__ alignas(16) float alf[352];                   // edge weights (aliased as cnt during build)
__shared__ alignas(16) float bl[64];                     // padded bias
__shared__ float sn[40];
__shared__ float dn[40];                                 // d_n, then 1/den
__shared__ unsigned char csr_src[352];
__shared__ unsigned short csr_ptr[40];

// ======================= fused GAT layer (per wave) =======================
template<int Fi, int Fo, int SIN, int SOUT, int SB>
__device__ __forceinline__ void layer(float x0,
                                      const float* __restrict__ W,   // [Fi][Fo] row-major
                                      const float* __restrict__ as_,
                                      const float* __restrict__ ad_,
                                      const float* __restrict__ bias,
                                      unsigned short* __restrict__ f_row,
                                      int res_off, int out_off, int lane) {
  constexpr int  OQ  = (Fo + 3) / 4;               // output quads
  constexpr int  FoP = OQ * 4;                     // padded Fo
  constexpr bool PP  = (OQ & (OQ - 1)) == 0;       // pow2 -> register pooling

  bl[lane] = (lane < Fo) ? bias[lane] : 0.f;       // padded bias stage

  // ---------- P1: h1 = h0 @ W (lane = node, W via scalar loads) ----------
  // ---------- P2: attention scalars + h1 -> B (bf16) ----------
  if (lane < NPG) {
    float h1r[FoP];
#pragma unroll
    for (int o = 0; o < FoP; ++o) h1r[o] = 0.f;
    if constexpr (Fi == 1) {
#pragma unroll
      for (int o = 0; o < Fo; ++o) h1r[o] = x0 * W[o];
    } else {
#pragma unroll
      for (int iq = 0; iq < Fi / 4; ++iq) {
        uint2 u = *(const uint2*)&Abuf16[lane * SIN + 4 * iq];
        float xv4[4];
        xv4[0] = b2f_lo(u.x); xv4[1] = b2f_hi(u.x);
        xv4[2] = b2f_lo(u.y); xv4[3] = b2f_hi(u.y);
#pragma unroll
        for (int ii = 0; ii < 4; ++ii) {
          int i = 4 * iq + ii;
          float xv = xv4[ii];
#pragma unroll
          for (int op = 0; op < FoP / 2; ++op) {    // packed pairs -> v_pk_fma
            f32x2 wv;
            wv.x = (2 * op     < Fo) ? W[i * Fo + 2 * op]     : 0.f;
            wv.y = (2 * op + 1 < Fo) ? W[i * Fo + 2 * op + 1] : 0.f;
            f32x2 hv = *(f32x2*)&h1r[2 * op];
            hv += wv * xv;
            *(f32x2*)&h1r[2 * op] = hv;
          }
        }
      }
    }
    float s_ = 0.f, d_ = 0.f;
#pragma unroll
    for (int o = 0; o < Fo; ++o) { s_ += h1r[o] * as_[o]; d_ += h1r[o] * ad_[o]; }
    sn[lane] = s_; dn[lane] = d_;
#pragma unroll
    for (int q = 0; q < OQ; ++q) {                 // h1 -> B in bf16
      f32x4 v; v.x = h1r[4 * q]; v.y = h1r[4 * q + 1];
      v.z = h1r[4 * q + 2]; v.w = h1r[4 * q + 3];
      *(ushort4*)&Bbuf16[lane * SB + 4 * q] = pack4(v);
    }
  }
  wsync();

  // ---------- P3: per-dst softmax (1/den folded into P4) ----------
  if (lane < NPG) {
    int rs = csr_ptr[lane], re = csr_ptr[lane + 1];
    float dv = dn[lane];
    float m = -3.4e38f;
    for (int k = rs; k < re; ++k) {
      float e = sn[csr_src[k]] + dv;
      e = (e >= 0.f) ? e : 0.2f * e;               // leaky_relu 0.2
      alf[k] = e;
      m = fmaxf(m, e);
    }
    float den = 0.f;
    for (int k = rs; k < re; ++k) { float w = __expf(alf[k] - m); alf[k] = w; den += w; }
    dn[lane] = 1.f / (den + 1e-16f);
  }
  wsync();

  // ---------- P4: aggregate + bias + relu + res write + (pool acc) ----------
  f32x4 pm = {0.f, 0.f, 0.f, 0.f};                 // post-relu values >= 0
  for (int item = lane; item < NPG * OQ; item += 64) {
    int d = item / OQ, q = item - d * OQ;
    int rs = csr_ptr[d], re = csr_ptr[d + 1];
    f32x4 acc = {0.f, 0.f, 0.f, 0.f};
    for (int k = rs; k < re; ++k) {
      float w = alf[k];
      int s = csr_src[k];
      uint2 u = *(const uint2*)&Bbuf16[s * SB + 4 * q];
      acc.x += b2f_lo(u.x) * w; acc.y += b2f_hi(u.x) * w;
      acc.z += b2f_lo(u.y) * w; acc.w += b2f_hi(u.y) * w;
    }
    float inv = dn[d];
    f32x4 bv = *(const f32x4*)&bl[4 * q];
    acc = acc * inv + bv;
    f32x4 z = {0.f, 0.f, 0.f, 0.f};
    acc = vmax4(acc, z);
    ushort4 p = pack4(acc);
    *(ushort4*)&Abuf16[d * SOUT + 4 * q] = p;      // next layer input (bf16)
    if constexpr (Fo == 9) {                       // stride-9 rows: scalar stores
      const unsigned short* pe = (const unsigned short*)&p;
#pragma unroll
      for (int j = 0; j < 4; ++j)
        if (4 * q + j < 9) f_row[res_off + d * 9 + 4 * q + j] = pe[j];
    } else {                                       // aligned 8B store
      *(ushort4*)&f_row[res_off + d * Fo + 4 * q] = p;
    }
    if constexpr (PP) pm = vmax4(pm, acc);
  }
  wsync();

  // ---------- P5: per-graph max pool ----------
  if constexpr (PP) {
    // lane's q-class is fixed across its P4 items (64 % OQ == 0): reduce
    // across d-groups with shfl_xor, lanes 0..OQ-1 hold the result.
#pragma unroll
    for (int st = OQ; st < 64; st <<= 1) {
      f32x4 o;
      o.x = __shfl_xor(pm.x, st); o.y = __shfl_xor(pm.y, st);
      o.z = __shfl_xor(pm.z, st); o.w = __shfl_xor(pm.w, st);
      pm = vmax4(pm, o);
    }
    if (lane < OQ) *(ushort4*)&f_row[out_off + 4 * lane] = pack4(pm);
  } else {
    int g = lane >> 4, q = lane & 15;
    if (q < OQ) {
      f32x4 m = {0.f, 0.f, 0.f, 0.f};
      for (int r = g; r < NPG; r += 4) {
        uint2 u = *(const uint2*)&Abuf16[r * SOUT + 4 * q];
        f32x4 v; v.x = b2f_lo(u.x); v.y = b2f_hi(u.x);
        v.z = b2f_lo(u.y); v.w = b2f_hi(u.y);
        m = vmax4(m, v);
      }
#pragma unroll
      for (int j = 0; j < 4; ++j) {
        float t;
        t = __shfl_xor(m[j], 16); m[j] = fmaxf(m[j], t);
        t = __shfl_xor(m[j], 32); m[j] = fmaxf(m[j], t);
      }
      if (g == 0) {
#pragma unroll
        for (int j = 0; j < 4; ++j)
          if (4 * q + j < Fo) f_row[out_off + 4 * q + j] = f2b(m[j]);
      }
    }
  }
}

// =========================== fused GAT kernel ===========================
__global__ __launch_bounds__(64, 3) void gat_fused(
    const float* __restrict__ x, const int* __restrict__ ei,
    const float* __restrict__ W1, const float* __restrict__ as1, const float* __restrict__ ad1, const float* __restrict__ b1,
    const float* __restrict__ W2, const float* __restrict__ as2, const float* __restrict__ ad2, const float* __restrict__ b2,
    const float* __restrict__ W3, const float* __restrict__ as3, const float* __restrict__ ad3, const float* __restrict__ b3,
    const float* __restrict__ W4, const float* __restrict__ as4, const float* __restrict__ ad4, const float* __restrict__ b4,
    unsigned short* __restrict__ f) {
  const int b = blockIdx.x;
  const int lane = threadIdx.x;                    // one wave per graph
  const int base = b * NPG;
  const int* srcg = ei + (size_t)b * EPG;
  const int* dstg = ei + E0 + (size_t)b * EPG;
  unsigned short* f_row = f + (size_t)b * KP;
  int* cnt = (int*)alf;                            // alias: alf unused until P3

  // x load, res0, out0, zero columns (k=39 and 4561..4607 under the permuted
  // layout: one zero column inserted at 39 makes all later blocks 4-aligned)
  float xv = 0.f;
  if (lane < NPG) {
    xv = x[(size_t)base + lane];
    f_row[lane] = f2b(xv);
  }
  if (lane == 0) f_row[39] = 0;
  if (lane < KP - 4561) f_row[4561 + lane] = 0;
  float mx = (lane < NPG) ? xv : -3.4e38f;
#pragma unroll
  for (int st = 1; st < 64; st <<= 1) { float t = __shfl_xor(mx, st); mx = fmaxf(mx, t); }
  if (lane == 0) f_row[4447] = f2b(mx);            // out0 = max over raw x
  if (lane < NPG) cnt[lane] = 1;                   // self loop pre-count
  wsync();

  // degree count (edges stashed in registers for the scatter pass)
  int es[5], ed[5];
#pragma unroll
  for (int it = 0; it < 5; ++it) {
    int e = lane + 64 * it;
    if (e < EPG) {
      int s = srcg[e] - base, d = dstg[e] - base;
      s = min(max(s, 0), NPG - 1);
      d = min(max(d, 0), NPG - 1);
      es[it] = s; ed[it] = d;
      atomicAdd(&cnt[d], 1);
    } else { es[it] = -1; ed[it] = 0; }
  }
  wsync();

  // exclusive prefix sum via wave scan
  int c = (lane < NPG) ? cnt[lane] : 0;
  int v = c;
#pragma unroll
  for (int off = 1; off < 64; off <<= 1) { int t = __shfl_up(v, off); if (lane >= off) v += t; }
  int excl = v - c;
  if (lane < NPG) csr_ptr[lane] = (unsigned short)excl;
  if (lane == NPG - 1) csr_ptr[NPG] = (unsigned short)EDG;   // total is always 351
  wsync();
  if (lane < NPG) cnt[lane] = excl;                // running positions
  wsync();

  // scatter: self loops + edges
  if (lane < NPG) { int p = atomicAdd(&cnt[lane], 1); csr_src[p] = (unsigned char)lane; }
#pragma unroll
  for (int it = 0; it < 5; ++it) {
    if (es[it] >= 0) {
      int p = atomicAdd(&cnt[ed[it]], 1);
      p = min(p, EDG - 1);
      csr_src[p] = (unsigned char)es[it];
    }
  }
  wsync();

  //     Fi  Fo  SIN SOUT SB          res_off  out_off
  layer< 1,  8,  12, 12,  12>(xv, W1, as1, ad1, b1, f_row, 40,   4448, lane);
  layer< 8, 64,  12, 68,  68>(0,  W2, as2, ad2, b2, f_row, 352,  4456, lane);
  layer<64, 32,  68, 36,  36>(0,  W3, as3, ad3, b3, f_row, 2848, 4520, lane);
  layer<32,  9,  36, 12,  12>(0,  W4, as4, ad4, b4, f_row, 4096, 4552, lane);
}

// ================= weight transpose + bf16 cast (per launch) =================
// PERM: apply the f-column permutation (insert zero col at k=39, shift +1)
template<bool PERM>
__global__ __launch_bounds__(256) void tcast(const float* __restrict__ in,
                                             unsigned short* __restrict__ out,
                                             int K, int NN, int Kpad) {
  __shared__ float tile[64 * 65];
  const int k0 = blockIdx.x * 64, n0 = blockIdx.y * 64;
  const int tid = threadIdx.x;
#pragma unroll
  for (int i = 0; i < 16; ++i) {
    int idx = i * 256 + tid;
    int r = idx >> 6, c = idx & 63;
    int k = k0 + r;
    int ko;
    if constexpr (PERM) {
      ko = (k < 39) ? k : ((k == 39 || k > FDIM) ? -1 : k - 1);
    } else {
      ko = (k < K) ? k : -1;
    }
    tile[r * 65 + c] = (ko >= 0) ? in[(size_t)ko * NN + n0 + c] : 0.f;
  }
  __syncthreads();
#pragma unroll
  for (int i = 0; i < 16; ++i) {
    int idx = i * 256 + tid;
    int r = idx >> 6, c = idx & 63;    // r: n-offset, c: k-offset
    out[(size_t)(n0 + r) * Kpad + k0 + c] = f2b(tile[c * 65 + r]);
  }
}

// =========================== bf16 MFMA GEMM ===========================
template<bool OUT_BF16>
__global__ __launch_bounds__(256) void mfma_gemm(const unsigned short* __restrict__ A,
    const unsigned short* __restrict__ Bt, unsigned short* __restrict__ Cb,
    float* __restrict__ Cf, const float* __restrict__ bias, int K, int N) {
  __shared__ alignas(16) unsigned short As[128 * 32];
  __shared__ alignas(16) unsigned short Bs[128 * 32];
  const int tid = threadIdx.x;
  const int lane = tid & 63;
  const int wave = tid >> 6;
  const int wy = wave >> 1, wx = wave & 1;
  const int m0 = blockIdx.y * 128, n0 = blockIdx.x * 128;

  f32x4 acc[4][4];
  const f32x4 z = {0.f, 0.f, 0.f, 0.f};
#pragma unroll
  for (int i = 0; i < 4; ++i)
#pragma unroll
    for (int j = 0; j < 4; ++j) acc[i][j] = z;

  const int lr = lane >> 2;
  const int lc = (lane & 3) * 8;
  const int q8 = (lane >> 4) * 8;
  const int rm = lane & 15;

  for (int k0 = 0; k0 < K; k0 += 32) {
    __syncthreads();
#pragma unroll
    for (int t = 0; t < 2; ++t) {
      int r0 = wave * 32 + t * 16;
      const unsigned short* ga = A  + (size_t)(m0 + r0 + lr) * K + k0 + lc;
      const unsigned short* gb = Bt + (size_t)(n0 + r0 + lr) * K + k0 + lc;
      __builtin_amdgcn_global_load_lds(
          (const __attribute__((address_space(1))) unsigned int*)(const void*)ga,
          (__attribute__((address_space(3))) unsigned int*)(void*)&As[r0 * 32], 16, 0, 0);
      __builtin_amdgcn_global_load_lds(
          (const __attribute__((address_space(1))) unsigned int*)(const void*)gb,
          (__attribute__((address_space(3))) unsigned int*)(void*)&Bs[r0 * 32], 16, 0, 0);
    }
    __syncthreads();
    bf16x8 af[4], bfr[4];
#pragma unroll
    for (int i = 0; i < 4; ++i) {
      af[i]  = *(const bf16x8*)&As[(wy * 64 + i * 16 + rm) * 32 + q8];
      bfr[i] = *(const bf16x8*)&Bs[(wx * 64 + i * 16 + rm) * 32 + q8];
    }
#pragma unroll
    for (int i = 0; i < 4; ++i)
#pragma unroll
      for (int j = 0; j < 4; ++j)
        acc[i][j] = __builtin_amdgcn_mfma_f32_16x16x32_bf16(af[i], bfr[j], acc[i][j], 0, 0, 0);
  }
  const int q4 = (lane >> 4) * 4;
#pragma unroll
  for (int i = 0; i < 4; ++i) {
#pragma unroll
    for (int j = 0; j < 4; ++j) {
      int row = m0 + wy * 64 + i * 16 + q4;
      int col = n0 + wx * 64 + j * 16 + rm;
      float bv = bias[col];
#pragma unroll
      for (int v = 0; v < 4; ++v) {
        float val = fmaxf(acc[i][j][v] + bv, 0.f);
        if constexpr (OUT_BF16) Cb[(size_t)(row + v) * N + col] = f2b(val);
        else                    Cf[(size_t)(row + v) * N + col] = val;
      }
    }
  }
}

// =========================== final 128->9 layer ===========================
__global__ __launch_bounds__(256) void mlp3(const float* __restrict__ g2,
                                            const float* __restrict__ w3,
                                            const float* __restrict__ b3,
                                            float* __restrict__ out) {
  __shared__ float gs[64 * 130];
  __shared__ float ws3[128 * 9];
  const int r0 = blockIdx.x * 64;
  const int tid = threadIdx.x;
  for (int i = tid; i < 64 * 128; i += 256)
    gs[(i >> 7) * 130 + (i & 127)] = g2[(size_t)r0 * 128 + i];
  for (int i = tid; i < 128 * 9; i += 256) ws3[i] = w3[i];
  __syncthreads();
  for (int idx = tid; idx < 64 * 9; idx += 256) {
    int r = idx / 9, c = idx - r * 9;
    float acc = b3[c];
#pragma unroll 8
    for (int k = 0; k < 128; ++k) acc += gs[r * 130 + k] * ws3[k * 9 + c];
    out[(size_t)(r0 + r) * 9 + c] = acc;
  }
}

// =========================== launch ===========================
extern "C" void kernel_launch(void* const* d_in, const int* in_sizes, int n_in,
                              void* d_out, int out_size, void* d_ws, size_t ws_size,
                              hipStream_t stream) {
  const float* x   = (const float*)d_in[0];
  const int*   ei  = (const int*)d_in[1];
  const float* W1  = (const float*)d_in[3];
  const float* as1 = (const float*)d_in[4];
  const float* ad1 = (const float*)d_in[5];
  const float* b1  = (const float*)d_in[6];
  const float* W2  = (const float*)d_in[7];
  const float* as2 = (const float*)d_in[8];
  const float* ad2 = (const float*)d_in[9];
  const float* b2  = (const float*)d_in[10];
  const float* W3  = (const float*)d_in[11];
  const float* as3 = (const float*)d_in[12];
  const float* ad3 = (const float*)d_in[13];
  const float* b3  = (const float*)d_in[14];
  const float* W4  = (const float*)d_in[15];
  const float* as4 = (const float*)d_in[16];
  const float* ad4 = (const float*)d_in[17];
  const float* b4  = (const float*)d_in[18];
  const float* lw1 = (const float*)d_in[19];
  const float* lb1 = (const float*)d_in[20];
  const float* lw2 = (const float*)d_in[21];
  const float* lb2 = (const float*)d_in[22];
  const float* lw3 = (const float*)d_in[23];
  const float* lb3 = (const float*)d_in[24];
  float* out = (float*)d_out;

  // workspace carve-up (bf16 stored as u16)
  unsigned short* f   = (unsigned short*)d_ws;            // [8192][4608] bf16
  unsigned short* w1t = f   + (size_t)NGRAPH * KP;        // [1024][4608] bf16
  unsigned short* w2t = w1t + (size_t)1024 * KP;          // [128][1024]  bf16
  unsigned short* g1  = w2t + (size_t)128 * 1024;         // [8192][1024] bf16
  float*          g2  = (float*)(g1 + (size_t)NGRAPH * 1024); // [8192][128] f32

  tcast<true ><<<dim3(KP / 64, 1024 / 64), 256, 0, stream>>>(lw1, w1t, FDIM, 1024, KP);
  tcast<false><<<dim3(1024 / 64, 128 / 64), 256, 0, stream>>>(lw2, w2t, 1024, 128, 1024);

  gat_fused<<<NGRAPH, 64, 0, stream>>>(x, ei,
      W1, as1, ad1, b1, W2, as2, ad2, b2, W3, as3, ad3, b3, W4, as4, ad4, b4, f);

  mfma_gemm<true ><<<dim3(1024 / 128, NGRAPH / 128), 256, 0, stream>>>(
      f, w1t, g1, nullptr, lb1, KP, 1024);
  mfma_gemm<false><<<dim3(128 / 128, NGRAPH / 128), 256, 0, stream>>>(
      g1, w2t, nullptr, g2, lb2, 1024, 128);

  mlp3<<<NGRAPH / 64, 256, 0, stream>>>(g2, lw3, lb3, out);
}